// Round 1
// baseline (628.060 us; speedup 1.0000x reference)
//
#include <hip/hip_runtime.h>
#include <hip/hip_bf16.h>

#define N_AGENTS 50000
#define N_NEI    1600000
#define ROWS     128
#define PHI_TILES (N_NEI / ROWS)   // 12500, exact
#define PHI_GRID  1024             // persistent blocks, ~3/CU resident, grid-stride

typedef __bf16 bf16_t;
typedef __attribute__((ext_vector_type(8))) __bf16 bf16x8;
typedef __attribute__((ext_vector_type(4))) float  f32x4;

#define SA 72   // bf16 tile leading dim (64+8): breaks 128B-stride bank aliasing, keeps 16B align
#define SO 66   // fp32 out tile leading dim

// ---------------------------------------------------------------------------
// phi kernel (persistent): weights staged to LDS ONCE, all B-fragments of both
// GEMMs hoisted to registers (64 VGPR), biases in registers. Then grid-stride
// over 128-row tiles:
//   X(128x64) -> H1 = relu(X@W1+b1) -> H2 = H1@W2+b2  (bf16 MFMA, fp32 accum)
//   per-wave segmented sum over its own 32 rows -> atomicAdd into summ.
// outb aliases A+Wt: safe because Wt is never re-read after the register hoist
// and every wave preloads its GEMM2 A-fragments before the aliasing barrier.
// ---------------------------------------------------------------------------
__global__ __launch_bounds__(256, 3) void phi_kernel(
    const float* __restrict__ nb,
    const float* __restrict__ w1g, const float* __restrict__ b1g,
    const float* __restrict__ w2g, const float* __restrict__ b2g,
    const int* __restrict__ seg, float* __restrict__ summ)
{
  __shared__ __align__(16) union {
    struct {
      bf16_t A[ROWS * SA];      // 18432 B : X tile, then H1 tile (bf16)
      bf16_t Wt[2][64 * SA];    // 18432 B : W1^T, W2^T (bf16, [n][k]) — read once
    } s;
    float outb[ROWS * SO];      // 33792 B : H2 fp32 (aliases A + part of Wt)
  } u;
  __shared__ int sid[ROWS + 4];

  const int tid  = threadIdx.x;
  const int w    = tid >> 6;      // wave 0..3
  const int lane = tid & 63;
  const int m16  = lane & 15;     // A row / B col / D col within 16-tile
  const int q    = lane >> 4;     // quad 0..3
  const int rb   = w * 32;        // this wave's 32-row stripe

  // ---- one-time: stage weights transposed to [n][k], bf16
  for (int i = tid; i < 4096; i += 256) {
    int k = i >> 6, n = i & 63;
    u.s.Wt[0][n * SA + k] = (bf16_t)w1g[i];
    u.s.Wt[1][n * SA + k] = (bf16_t)w2g[i];
  }
  // ---- one-time: per-lane bias registers (lane's D-columns are tn*16+m16)
  float b1r[4], b2r[4];
  #pragma unroll
  for (int tn = 0; tn < 4; ++tn) {
    b1r[tn] = b1g[tn * 16 + m16];
    b2r[tn] = b2g[tn * 16 + m16];
  }
  __syncthreads();

  // ---- one-time: hoist ALL B fragments (both GEMMs) into registers.
  // After this, Wt is dead and outb may clobber it each tile.
  bf16x8 bf1[4][2], bf2[4][2];
  #pragma unroll
  for (int tn = 0; tn < 4; ++tn)
    #pragma unroll
    for (int kb = 0; kb < 2; ++kb) {
      bf1[tn][kb] = *(const bf16x8*)&u.s.Wt[0][(tn * 16 + m16) * SA + kb * 32 + q * 8];
      bf2[tn][kb] = *(const bf16x8*)&u.s.Wt[1][(tn * 16 + m16) * SA + kb * 32 + q * 8];
    }
  // NOTE: no barrier needed here — first aliasing outb write happens after
  // iteration 0's mid-GEMM barrier, which every wave reaches only after its
  // own bf1/bf2 loads (program order).

  for (int t = blockIdx.x; t < PHI_TILES; t += gridDim.x) {
    const int base_row = t * ROWS;

    // ---- stage segment ids + X tile (coalesced, 32B/lane), convert to bf16
    if (tid < ROWS) sid[tid] = seg[base_row + tid];
    {
      const float4* np4 = (const float4*)(nb + (size_t)base_row * 64);
      #pragma unroll
      for (int it = 0; it < 4; ++it) {
        int j = tid * 2 + it * 512;        // float4 pair index within tile
        float4 v0 = np4[j], v1 = np4[j + 1];
        int row = j >> 4, col = (j & 15) * 4;
        bf16x8 p = { (bf16_t)v0.x, (bf16_t)v0.y, (bf16_t)v0.z, (bf16_t)v0.w,
                     (bf16_t)v1.x, (bf16_t)v1.y, (bf16_t)v1.z, (bf16_t)v1.w };
        *(bf16x8*)&u.s.A[row * SA + col] = p;   // 16B LDS write, 16B aligned
      }
    }
    __syncthreads();   // staging visible to all waves

    // ================= GEMM1: H1 = relu(X @ W1 + b1) =================
    bf16x8 afr[2][2];
    f32x4  acc[2][4];
    #pragma unroll
    for (int tm = 0; tm < 2; ++tm)
      #pragma unroll
      for (int kb = 0; kb < 2; ++kb)
        afr[tm][kb] = *(const bf16x8*)&u.s.A[(rb + tm * 16 + m16) * SA + kb * 32 + q * 8];
    #pragma unroll
    for (int tm = 0; tm < 2; ++tm)
      #pragma unroll
      for (int tn = 0; tn < 4; ++tn) {
        f32x4 a = {0.f, 0.f, 0.f, 0.f};
        a = __builtin_amdgcn_mfma_f32_16x16x32_bf16(afr[tm][0], bf1[tn][0], a, 0, 0, 0);
        a = __builtin_amdgcn_mfma_f32_16x16x32_bf16(afr[tm][1], bf1[tn][1], a, 0, 0, 0);
        acc[tm][tn] = a;
      }
    // write H1 back over X (bf16). Wave touches only its own rows -> no barrier.
    #pragma unroll
    for (int tm = 0; tm < 2; ++tm)
      #pragma unroll
      for (int tn = 0; tn < 4; ++tn) {
        float bv = b1r[tn];
        #pragma unroll
        for (int i = 0; i < 4; ++i) {
          float hv = fmaxf(acc[tm][tn][i] + bv, 0.f);
          u.s.A[(rb + tm * 16 + q * 4 + i) * SA + tn * 16 + m16] = (bf16_t)hv;
        }
      }

    // ================= GEMM2: H2 = H1 @ W2 + b2 =================
    // Preload A fragments before the barrier: outb aliases A (+dead Wt).
    #pragma unroll
    for (int tm = 0; tm < 2; ++tm)
      #pragma unroll
      for (int kb = 0; kb < 2; ++kb)
        afr[tm][kb] = *(const bf16x8*)&u.s.A[(rb + tm * 16 + m16) * SA + kb * 32 + q * 8];
    __syncthreads();   // everyone done reading A; outb may now overwrite

    #pragma unroll
    for (int tm = 0; tm < 2; ++tm)
      #pragma unroll
      for (int tn = 0; tn < 4; ++tn) {
        f32x4 a = {0.f, 0.f, 0.f, 0.f};
        a = __builtin_amdgcn_mfma_f32_16x16x32_bf16(afr[tm][0], bf2[tn][0], a, 0, 0, 0);
        a = __builtin_amdgcn_mfma_f32_16x16x32_bf16(afr[tm][1], bf2[tn][1], a, 0, 0, 0);
        acc[tm][tn] = a;
      }
    #pragma unroll
    for (int tm = 0; tm < 2; ++tm)
      #pragma unroll
      for (int tn = 0; tn < 4; ++tn) {
        float bv = b2r[tn];
        #pragma unroll
        for (int i = 0; i < 4; ++i)
          u.outb[(rb + tm * 16 + q * 4 + i) * SO + tn * 16 + m16] = acc[tm][tn][i] + bv;
      }

    // ---- segmented reduction: wave w owns rows [rb, rb+32), lane owns col=lane.
    // segment_ids sorted -> detect run boundaries; one atomic per run.
    float racc = 0.f;
    for (int r = rb; r < rb + 32; ++r) {
      racc += u.outb[r * SO + lane];
      int sr = sid[r];
      if (r == rb + 31 || sid[r + 1] != sr) {   // short-circuit: no sid[128] read
        atomicAdd(summ + (size_t)sr * 64 + lane, racc);
        racc = 0.f;
      }
    }
    __syncthreads();   // protect outb/sid/A before next tile's staging
  }
}

// ---------------------------------------------------------------------------
// rho kernel: fp32 throughout (accuracy on pooled values). One thread/agent.
// W1 transposed in LDS to [n][k] (pad 68) -> inner loop reads 16 broadcast
// ds_read_b128 per n instead of 64 scalar stride-64 reads.
// ---------------------------------------------------------------------------
__global__ __launch_bounds__(256) void rho_kernel(
    const float* __restrict__ summ,
    const float* __restrict__ w1g, const float* __restrict__ b1g,
    const float* __restrict__ w2g, const float* __restrict__ b2g,
    float* __restrict__ out)
{
  __shared__ float sw1t[64 * 68];   // [n][k], pad to 68 keeps float4 16B-aligned
  __shared__ float sw2[128];
  __shared__ float sb1[64];
  __shared__ float sb2[2];
  const int tid = threadIdx.x;
  for (int i = tid; i < 4096; i += 256) {
    int n = i >> 6, k = i & 63;     // consecutive lanes -> consecutive k: conflict-free LDS writes
    sw1t[n * 68 + k] = w1g[k * 64 + n];   // gather from L1/L2-hot 16KB matrix
  }
  if (tid < 128) sw2[tid] = w2g[tid];
  if (tid < 64)  sb1[tid] = b1g[tid];
  if (tid < 2)   sb2[tid] = b2g[tid];
  __syncthreads();

  int a = blockIdx.x * 256 + tid;
  if (a >= N_AGENTS) return;

  float x[64];
  const float4* xr = (const float4*)(summ + (size_t)a * 64);
  #pragma unroll
  for (int i = 0; i < 16; ++i) {
    float4 v = xr[i];
    x[4*i] = v.x; x[4*i+1] = v.y; x[4*i+2] = v.z; x[4*i+3] = v.w;
  }

  float o0 = sb2[0], o1 = sb2[1];
  for (int n = 0; n < 64; ++n) {
    const float4* wr = (const float4*)&sw1t[n * 68];
    float a0 = sb1[n], a1 = 0.f, a2 = 0.f, a3 = 0.f;
    #pragma unroll
    for (int kq = 0; kq < 16; ++kq) {
      float4 wv = wr[kq];              // same addr across wave -> LDS broadcast
      a0 = fmaf(x[4*kq],     wv.x, a0);
      a1 = fmaf(x[4*kq + 1], wv.y, a1);
      a2 = fmaf(x[4*kq + 2], wv.z, a2);
      a3 = fmaf(x[4*kq + 3], wv.w, a3);
    }
    float h = fmaxf((a0 + a1) + (a2 + a3), 0.f);
    o0 = fmaf(h, sw2[2 * n],     o0);
    o1 = fmaf(h, sw2[2 * n + 1], o1);
  }
  *(float2*)(out + (size_t)a * 2) = make_float2(o0, o1);
}

// ---------------------------------------------------------------------------
extern "C" void kernel_launch(void* const* d_in, const int* in_sizes, int n_in,
                              void* d_out, int out_size, void* d_ws, size_t ws_size,
                              hipStream_t stream) {
  const float* neighbors = (const float*)d_in[0];
  const float* phi_w1    = (const float*)d_in[1];
  const float* phi_b1    = (const float*)d_in[2];
  const float* phi_w2    = (const float*)d_in[3];
  const float* phi_b2    = (const float*)d_in[4];
  const float* rho_w1    = (const float*)d_in[5];
  const float* rho_b1    = (const float*)d_in[6];
  const float* rho_w2    = (const float*)d_in[7];
  const float* rho_b2    = (const float*)d_in[8];
  const int*   seg       = (const int*)d_in[9];
  float* out  = (float*)d_out;
  float* summ = (float*)d_ws;   // 50000 x 64 fp32 = 12.8 MB scratch

  hipMemsetAsync(summ, 0, (size_t)N_AGENTS * 64 * sizeof(float), stream);
  phi_kernel<<<PHI_GRID, 256, 0, stream>>>(neighbors, phi_w1, phi_b1,
                                           phi_w2, phi_b2, seg, summ);
  rho_kernel<<<(N_AGENTS + 255) / 256, 256, 0, stream>>>(summ, rho_w1, rho_b1,
                                                         rho_w2, rho_b2, out);
}

// Round 2
// 601.383 us; speedup vs baseline: 1.0444x; 1.0444x over previous
//
#include <hip/hip_runtime.h>
#include <hip/hip_bf16.h>

#define N_AGENTS 50000
#define N_NEI    1600000
#define ROWS     128
#define PHI_BLOCKS (N_NEI / ROWS)   // 12500, exact. Independent blocks: scheduler
                                    // overlaps staging/compute across blocks (the
                                    // persistent-grid variant regressed +23us).

typedef __bf16 bf16_t;
typedef __attribute__((ext_vector_type(8))) __bf16 bf16x8;
typedef __attribute__((ext_vector_type(4))) __bf16 bf16x4;
typedef __attribute__((ext_vector_type(2))) __bf16 bf16x2;
typedef __attribute__((ext_vector_type(4))) float  f32x4;

#define SA 72   // bf16 tile leading dim (64+8): row stride 144B = 36 words; frag
                // reads/writes land uniform 8-per-bank (conflict-free floor)
#define SO 68   // fp32 out tile leading dim: 272B row stride keeps b128 16B-aligned

#define SUMM_BYTES ((size_t)N_AGENTS * 64 * sizeof(float))   // 12.8 MB, 16B-aligned

// ---------------------------------------------------------------------------
// prep kernel: once per launch, transpose+convert weights to bf16 [n][k] dense
// in workspace. Removes the per-block transposed/conflicted weight staging
// (12500x). 2 blocks (one per matrix); cost ~2us.
// ---------------------------------------------------------------------------
__global__ __launch_bounds__(256) void prep_weights(
    const float* __restrict__ w1g, const float* __restrict__ w2g,
    bf16_t* __restrict__ gWt)
{
  __shared__ float s[4096];
  const int tid = threadIdx.x;
  const float* src = blockIdx.x ? w2g : w1g;
  bf16_t* dst = gWt + blockIdx.x * 4096;
  for (int i = tid; i < 4096; i += 256) s[i] = src[i];   // coalesced
  __syncthreads();
  for (int i = tid; i < 2048; i += 256) {
    int n = i >> 5, k2 = (i & 31) * 2;
    bf16x2 p = { (bf16_t)s[k2 * 64 + n], (bf16_t)s[(k2 + 1) * 64 + n] };
    *(bf16x2*)&dst[n * 64 + k2] = p;                     // coalesced global write
  }
}

// ---------------------------------------------------------------------------
// phi kernel: per block of 128 sorted neighbor rows:
//   X(128x64) -> H1 = relu(X@W1+b1) -> H2 = H1@W2+b2  (bf16 MFMA, fp32 accum)
//   then per-wave segmented sum over its own 32 rows -> atomicAdd into summ.
//
// OPERAND-SWAP: mfma(A=weight-frag, B=row-frag) computes the transposed tile;
// D layout (col=lane&15 -> neighbor row, reg q*4+i -> 4 CONSECUTIVE feature
// cols) lets H1 store as packed ds_write_b64 and H2 as ds_write_b128 instead
// of 32 scalar stores each. LDS read patterns are unchanged (A/B fragments
// have identical per-lane shape), so numerics are bit-identical to the
// verified non-swapped kernel.
// ---------------------------------------------------------------------------
__global__ __launch_bounds__(256) void phi_kernel(
    const float* __restrict__ nb,
    const bf16_t* __restrict__ gWt,
    const float* __restrict__ b1g, const float* __restrict__ b2g,
    const int* __restrict__ seg, float* __restrict__ summ)
{
  __shared__ __align__(16) union {
    struct {
      bf16_t A[ROWS * SA];      // 18432 B : X tile, then H1 tile (bf16)
      bf16_t Wt[2][64 * SA];    // 18432 B : W1^T, W2^T (bf16, [n][k])
    } s;
    float outb[ROWS * SO];      // 34816 B : H2 fp32 (aliases A + Wt)
  } u;
  __shared__ int sid[ROWS + 4];

  const int tid  = threadIdx.x;
  const int w    = tid >> 6;      // wave 0..3
  const int lane = tid & 63;
  const int m16  = lane & 15;     // fragment row/col index within 16-tile
  const int q    = lane >> 4;     // quad 0..3
  const int rb   = w * 32;        // this wave's 32-row stripe
  const int base_row = blockIdx.x * ROWS;

  // ---- stage segment ids
  if (tid < ROWS) sid[tid] = seg[base_row + tid];

  // ---- stage pre-transposed bf16 weights: 4 x (b128 load + conflict-free b128 LDS write)
  for (int i = tid; i < 1024; i += 256) {
    int mat = i >> 9, r = i & 511;
    int n = r >> 3, c = r & 7;
    bf16x8 v = *(const bf16x8*)&gWt[mat * 4096 + n * 64 + c * 8];
    *(bf16x8*)&u.s.Wt[mat][n * SA + c * 8] = v;
  }

  // ---- per-lane bias vectors: output col c = tn*16 + q*4 + i
  float4 b1v[4];
  #pragma unroll
  for (int tn = 0; tn < 4; ++tn)
    b1v[tn] = *(const float4*)(b1g + tn * 16 + q * 4);

  // ---- stage X tile (coalesced 32B/lane), convert, b128 LDS writes
  {
    const float4* np4 = (const float4*)(nb + (size_t)base_row * 64);
    #pragma unroll
    for (int it = 0; it < 4; ++it) {
      int j = tid * 2 + it * 512;          // even -> 16B-aligned LDS target
      float4 v0 = np4[j], v1 = np4[j + 1];
      int row = j >> 4, col = (j & 15) * 4;
      bf16x8 p = { (bf16_t)v0.x, (bf16_t)v0.y, (bf16_t)v0.z, (bf16_t)v0.w,
                   (bf16_t)v1.x, (bf16_t)v1.y, (bf16_t)v1.z, (bf16_t)v1.w };
      *(bf16x8*)&u.s.A[row * SA + col] = p;
    }
  }
  __syncthreads();

  bf16x8 wfr[4][2], xfr[2][2];
  f32x4  acc[2][4];

  // ================= GEMM1 (swapped): lane gets H1[r = rb+tm*16+m16][c = tn*16+q*4+i]
  #pragma unroll
  for (int tn = 0; tn < 4; ++tn)
    #pragma unroll
    for (int kb = 0; kb < 2; ++kb)
      wfr[tn][kb] = *(const bf16x8*)&u.s.Wt[0][(tn * 16 + m16) * SA + kb * 32 + q * 8];
  #pragma unroll
  for (int tm = 0; tm < 2; ++tm)
    #pragma unroll
    for (int kb = 0; kb < 2; ++kb)
      xfr[tm][kb] = *(const bf16x8*)&u.s.A[(rb + tm * 16 + m16) * SA + kb * 32 + q * 8];
  #pragma unroll
  for (int tm = 0; tm < 2; ++tm)
    #pragma unroll
    for (int tn = 0; tn < 4; ++tn) {
      f32x4 a = {0.f, 0.f, 0.f, 0.f};
      a = __builtin_amdgcn_mfma_f32_16x16x32_bf16(wfr[tn][0], xfr[tm][0], a, 0, 0, 0);
      a = __builtin_amdgcn_mfma_f32_16x16x32_bf16(wfr[tn][1], xfr[tm][1], a, 0, 0, 0);
      acc[tm][tn] = a;
    }
  // H1 writeback over X: 8 packed ds_write_b64 (4 consecutive cols of own row).
  // Wave touches only rows rb..rb+31; in-wave LDS program order -> no barrier.
  #pragma unroll
  for (int tm = 0; tm < 2; ++tm)
    #pragma unroll
    for (int tn = 0; tn < 4; ++tn) {
      bf16x4 p = { (bf16_t)fmaxf(acc[tm][tn][0] + b1v[tn].x, 0.f),
                   (bf16_t)fmaxf(acc[tm][tn][1] + b1v[tn].y, 0.f),
                   (bf16_t)fmaxf(acc[tm][tn][2] + b1v[tn].z, 0.f),
                   (bf16_t)fmaxf(acc[tm][tn][3] + b1v[tn].w, 0.f) };
      *(bf16x4*)&u.s.A[(rb + tm * 16 + m16) * SA + tn * 16 + q * 4] = p;
    }

  // ================= GEMM2 (swapped): preload all fragments before aliasing barrier
  float4 b2v[4];
  #pragma unroll
  for (int tn = 0; tn < 4; ++tn)
    b2v[tn] = *(const float4*)(b2g + tn * 16 + q * 4);
  #pragma unroll
  for (int tn = 0; tn < 4; ++tn)
    #pragma unroll
    for (int kb = 0; kb < 2; ++kb)
      wfr[tn][kb] = *(const bf16x8*)&u.s.Wt[1][(tn * 16 + m16) * SA + kb * 32 + q * 8];
  #pragma unroll
  for (int tm = 0; tm < 2; ++tm)
    #pragma unroll
    for (int kb = 0; kb < 2; ++kb)
      xfr[tm][kb] = *(const bf16x8*)&u.s.A[(rb + tm * 16 + m16) * SA + kb * 32 + q * 8];
  __syncthreads();   // everyone done reading A/Wt; outb may now overwrite them

  #pragma unroll
  for (int tm = 0; tm < 2; ++tm)
    #pragma unroll
    for (int tn = 0; tn < 4; ++tn) {
      f32x4 a = {0.f, 0.f, 0.f, 0.f};
      a = __builtin_amdgcn_mfma_f32_16x16x32_bf16(wfr[tn][0], xfr[tm][0], a, 0, 0, 0);
      a = __builtin_amdgcn_mfma_f32_16x16x32_bf16(wfr[tn][1], xfr[tm][1], a, 0, 0, 0);
      acc[tm][tn] = a;
    }
  // H2 store: 8 x ds_write_b128 (f32x4), bank-floor uniform.
  #pragma unroll
  for (int tm = 0; tm < 2; ++tm)
    #pragma unroll
    for (int tn = 0; tn < 4; ++tn) {
      f32x4 o = { acc[tm][tn][0] + b2v[tn].x, acc[tm][tn][1] + b2v[tn].y,
                  acc[tm][tn][2] + b2v[tn].z, acc[tm][tn][3] + b2v[tn].w };
      *(f32x4*)&u.outb[(rb + tm * 16 + m16) * SO + tn * 16 + q * 4] = o;
    }

  // ---- segmented reduction: wave w owns rows [rb, rb+32), lane owns col=lane.
  // Own-wave rows only -> no barrier needed after H2 store.
  float racc = 0.f;
  for (int r = rb; r < rb + 32; ++r) {
    racc += u.outb[r * SO + lane];
    int sr = sid[r];
    if (r == rb + 31 || sid[r + 1] != sr) {   // short-circuit: no sid[128] read
      atomicAdd(summ + (size_t)sr * 64 + lane, racc);
      racc = 0.f;
    }
  }
}

// ---------------------------------------------------------------------------
// rho kernel: fp32 throughout. W1 transposed in LDS to [n][k] (pad 68) ->
// inner loop is 16 broadcast ds_read_b128 per n (conflict-free, coalesced
// staging) instead of 64 scalar reads.
// ---------------------------------------------------------------------------
__global__ __launch_bounds__(256) void rho_kernel(
    const float* __restrict__ summ,
    const float* __restrict__ w1g, const float* __restrict__ b1g,
    const float* __restrict__ w2g, const float* __restrict__ b2g,
    float* __restrict__ out)
{
  __shared__ float sw1t[64 * 68];
  __shared__ float sw2[128];
  __shared__ float sb1[64];
  __shared__ float sb2[2];
  const int tid = threadIdx.x;
  for (int i = tid; i < 4096; i += 256) {
    int n = i >> 6, k = i & 63;          // lanes -> consecutive k: coalesced read? no:
    sw1t[n * 68 + k] = w1g[k * 64 + n];  // lanes consecutive k -> stride-64... keep
  }                                       // L2-hot 16KB; writes conflict-free
  if (tid < 128) sw2[tid] = w2g[tid];
  if (tid < 64)  sb1[tid] = b1g[tid];
  if (tid < 2)   sb2[tid] = b2g[tid];
  __syncthreads();

  int a = blockIdx.x * 256 + tid;
  if (a >= N_AGENTS) return;

  float x[64];
  const float4* xr = (const float4*)(summ + (size_t)a * 64);
  #pragma unroll
  for (int i = 0; i < 16; ++i) {
    float4 v = xr[i];
    x[4*i] = v.x; x[4*i+1] = v.y; x[4*i+2] = v.z; x[4*i+3] = v.w;
  }

  float o0 = sb2[0], o1 = sb2[1];
  for (int n = 0; n < 64; ++n) {
    const float4* wr = (const float4*)&sw1t[n * 68];
    float a0 = sb1[n], a1 = 0.f, a2 = 0.f, a3 = 0.f;
    #pragma unroll
    for (int kq = 0; kq < 16; ++kq) {
      float4 wv = wr[kq];              // uniform addr across wave -> LDS broadcast
      a0 = fmaf(x[4*kq],     wv.x, a0);
      a1 = fmaf(x[4*kq + 1], wv.y, a1);
      a2 = fmaf(x[4*kq + 2], wv.z, a2);
      a3 = fmaf(x[4*kq + 3], wv.w, a3);
    }
    float h = fmaxf((a0 + a1) + (a2 + a3), 0.f);
    o0 = fmaf(h, sw2[2 * n],     o0);
    o1 = fmaf(h, sw2[2 * n + 1], o1);
  }
  *(float2*)(out + (size_t)a * 2) = make_float2(o0, o1);
}

// ---------------------------------------------------------------------------
extern "C" void kernel_launch(void* const* d_in, const int* in_sizes, int n_in,
                              void* d_out, int out_size, void* d_ws, size_t ws_size,
                              hipStream_t stream) {
  const float* neighbors = (const float*)d_in[0];
  const float* phi_w1    = (const float*)d_in[1];
  const float* phi_b1    = (const float*)d_in[2];
  const float* phi_w2    = (const float*)d_in[3];
  const float* phi_b2    = (const float*)d_in[4];
  const float* rho_w1    = (const float*)d_in[5];
  const float* rho_b1    = (const float*)d_in[6];
  const float* rho_w2    = (const float*)d_in[7];
  const float* rho_b2    = (const float*)d_in[8];
  const int*   seg       = (const int*)d_in[9];
  float* out  = (float*)d_out;
  float* summ = (float*)d_ws;                                   // 12.8 MB scratch
  bf16_t* gWt = (bf16_t*)((char*)d_ws + SUMM_BYTES);            // 16 KB bf16 W^T

  hipMemsetAsync(summ, 0, SUMM_BYTES, stream);
  prep_weights<<<2, 256, 0, stream>>>(phi_w1, phi_w2, gWt);
  phi_kernel<<<PHI_BLOCKS, 256, 0, stream>>>(neighbors, gWt, phi_b1, phi_b2,
                                             seg, summ);
  rho_kernel<<<(N_AGENTS + 255) / 256, 256, 0, stream>>>(summ, rho_w1, rho_b1,
                                                         rho_w2, rho_b2, out);
}